// Round 1
// baseline (1958.092 us; speedup 1.0000x reference)
//
#include <hip/hip_runtime.h>
#include <math.h>

// Problem constants
#define TT 2048      // tgt_len
#define SS 2048      // src_len
#define BB 2         // batch
#define EE 1024      // embed dim
#define HH 16        // heads
#define DD 64        // head dim (DK == DV)
#define ZZ 32        // B*H
#define SCALING 0.125f
#define D_THRESH 3.8918202981106265f   // log(2000/40 - 1) = log(49)

// ---------------------------------------------------------------------------
// Shared helpers: 64x64 tile, 256 threads, 4x4 register microtile.
// LDS operand layout is transposed: At[k][r], Bt[k][c] so the inner loop is
// two ds_read_b128 + 16 v_fmac per k-step (outer-product microtile).
// ---------------------------------------------------------------------------

__device__ __forceinline__ void stage_T(const float* __restrict__ src, int stride,
                                        float* __restrict__ dst, int rL, int g)
{
    // loads 16 floats of row rL (4x float4), stores transposed dst[k][rL]
#pragma unroll
    for (int j4 = 0; j4 < 4; ++j4) {
        const int e0 = g * 16 + j4 * 4;
        const float4 val = *(const float4*)(src + (size_t)rL * stride + e0);
        dst[(e0 + 0) * 64 + rL] = val.x;
        dst[(e0 + 1) * 64 + rL] = val.y;
        dst[(e0 + 2) * 64 + rL] = val.z;
        dst[(e0 + 3) * 64 + rL] = val.w;
    }
}

__device__ __forceinline__ void mm16(const float* __restrict__ At,
                                     const float* __restrict__ Bt,
                                     int r0, int c0, float acc[4][4])
{
#pragma unroll 8
    for (int e = 0; e < 64; ++e) {
        const float4 a = *(const float4*)&At[e * 64 + r0];
        const float4 b = *(const float4*)&Bt[e * 64 + c0];
        acc[0][0] += a.x * b.x; acc[0][1] += a.x * b.y; acc[0][2] += a.x * b.z; acc[0][3] += a.x * b.w;
        acc[1][0] += a.y * b.x; acc[1][1] += a.y * b.y; acc[1][2] += a.y * b.z; acc[1][3] += a.y * b.w;
        acc[2][0] += a.z * b.x; acc[2][1] += a.z * b.y; acc[2][2] += a.z * b.z; acc[2][3] += a.z * b.w;
        acc[3][0] += a.w * b.x; acc[3][1] += a.w * b.y; acc[3][2] += a.w * b.z; acc[3][3] += a.w * b.w;
    }
}

// ---------------------------------------------------------------------------
// K1: qkv projection.  C[R][f] = sum_e X[R][e]*W[f][e];  R = t*B+b in [0,4096)
// Store transformed to ws layout [z=b*H+h][t][d], with (bias+)*scale applied.
// ---------------------------------------------------------------------------
__global__ __launch_bounds__(256) void proj_kernel(const float* __restrict__ X,
                                                   const float* __restrict__ W,
                                                   const float* __restrict__ bias,
                                                   float* __restrict__ out,
                                                   float scale)
{
    __shared__ __align__(16) float xt[64 * 64];
    __shared__ __align__(16) float wt[64 * 64];
    const int tid = threadIdx.x;
    const int R0 = blockIdx.x * 64;
    const int C0 = blockIdx.y * 64;
    const int rL = tid >> 2, g = tid & 3;
    const int r0 = (tid >> 4) * 4;
    const int c0 = (tid & 15) * 4;

    float acc[4][4] = {{0.f}};
    for (int kc = 0; kc < 16; ++kc) {
        const int E0 = kc * 64;
        __syncthreads();
        stage_T(X + (size_t)R0 * EE + E0, EE, xt, rL, g);
        stage_T(W + (size_t)C0 * EE + E0, EE, wt, rL, g);
        __syncthreads();
        mm16(xt, wt, r0, c0, acc);
    }

    const float4 bb = *(const float4*)(bias + C0 + c0);
    const int f = C0 + c0;           // multiple of 4, within one 64-block
    const int zcol = f >> 6;         // h
    const int d = f & 63;
#pragma unroll
    for (int i = 0; i < 4; ++i) {
        const int R = R0 + r0 + i;
        const int t = R >> 1, b = R & 1;
        float4 o;
        o.x = (acc[i][0] + bb.x) * scale;
        o.y = (acc[i][1] + bb.y) * scale;
        o.z = (acc[i][2] + bb.z) * scale;
        o.w = (acc[i][3] + bb.w) * scale;
        *(float4*)(out + ((size_t)(b * HH + zcol) * TT + t) * DD + d) = o;
    }
}

// ---------------------------------------------------------------------------
// K2: fused attention.  Per (z, 64-row q tile):
//   pass A: row max over S (recomputable QK^T)
//   pass B: recompute logits, e = kept ? exp(l-m) : 0, write e (unnormalized)
//           to attn_weights out, accumulate Z and P·V in registers.
// LDS: qt (persistent), kt (reused as e^T), vs.  48 KB total.
// ---------------------------------------------------------------------------
__global__ __launch_bounds__(256) void attn_kernel(const float* __restrict__ qw,
                                                   const float* __restrict__ kw,
                                                   const float* __restrict__ vw,
                                                   const int* __restrict__ mask,
                                                   float* __restrict__ eout,
                                                   float* __restrict__ av,
                                                   float* __restrict__ rcpz)
{
    __shared__ __align__(16) float qt[64 * 64];   // [d][r]
    __shared__ __align__(16) float kt[64 * 64];   // [d][s]; reused as e^T[s][r]
    __shared__ __align__(16) float vs[64 * 64];   // [s][d]
    const int tid = threadIdx.x;
    const int z = blockIdx.y;
    const int t0 = blockIdx.x * 64;
    const int rL = tid >> 2, g = tid & 3;
    const int r0 = (tid >> 4) * 4;   // rows r0..r0+3 of the tile
    const int c0 = (tid & 15) * 4;   // cols (s or d) c0..c0+3

    const float* qz = qw + (size_t)z * TT * DD;
    const float* kz = kw + (size_t)z * SS * DD;
    const float* vz = vw + (size_t)z * SS * DD;

    // stage q tile transposed (synced by first loop-top barrier)
    stage_T(qz + (size_t)t0 * DD, DD, qt, rL, g);

    float mx[4] = {-INFINITY, -INFINITY, -INFINITY, -INFINITY};

    // ---- pass A: row max ----
    for (int st = 0; st < SS / 64; ++st) {
        const int s0 = st * 64;
        __syncthreads();
        stage_T(kz + (size_t)s0 * DD, DD, kt, rL, g);
        __syncthreads();
        float lg[4][4] = {{0.f}};
        mm16(qt, kt, r0, c0, lg);
#pragma unroll
        for (int i = 0; i < 4; ++i) {
            const int4 mv = *(const int4*)(mask + (size_t)(t0 + r0 + i) * SS + s0 + c0);
            if (mv.x) mx[i] = fmaxf(mx[i], lg[i][0]);
            if (mv.y) mx[i] = fmaxf(mx[i], lg[i][1]);
            if (mv.z) mx[i] = fmaxf(mx[i], lg[i][2]);
            if (mv.w) mx[i] = fmaxf(mx[i], lg[i][3]);
        }
    }
    // reduce max across the 16 lanes sharing this row group
#pragma unroll
    for (int off = 1; off < 16; off <<= 1) {
#pragma unroll
        for (int i = 0; i < 4; ++i)
            mx[i] = fmaxf(mx[i], __shfl_xor(mx[i], off, 64));
    }

    // ---- pass B: e, Z, P·V ----
    float zp[4] = {0.f, 0.f, 0.f, 0.f};
    float acc[4][4] = {{0.f}};
    for (int st = 0; st < SS / 64; ++st) {
        const int s0 = st * 64;
        __syncthreads();
        stage_T(kz + (size_t)s0 * DD, DD, kt, rL, g);
        // vs: straight copy [s][d]
#pragma unroll
        for (int j4 = 0; j4 < 4; ++j4) {
            const int e0 = g * 16 + j4 * 4;
            const float4 val = *(const float4*)(vz + (size_t)(s0 + rL) * DD + e0);
            *(float4*)&vs[rL * 64 + e0] = val;
        }
        __syncthreads();
        float lg[4][4] = {{0.f}};
        mm16(qt, kt, r0, c0, lg);

        float ev[4][4];
#pragma unroll
        for (int i = 0; i < 4; ++i) {
            const int4 mv = *(const int4*)(mask + (size_t)(t0 + r0 + i) * SS + s0 + c0);
            const float th = mx[i] - D_THRESH;
            ev[i][0] = (mv.x && lg[i][0] >= th) ? __expf(lg[i][0] - mx[i]) : 0.f;
            ev[i][1] = (mv.y && lg[i][1] >= th) ? __expf(lg[i][1] - mx[i]) : 0.f;
            ev[i][2] = (mv.z && lg[i][2] >= th) ? __expf(lg[i][2] - mx[i]) : 0.f;
            ev[i][3] = (mv.w && lg[i][3] >= th) ? __expf(lg[i][3] - mx[i]) : 0.f;
            zp[i] += ev[i][0] + ev[i][1] + ev[i][2] + ev[i][3];
            float4 o;
            o.x = ev[i][0]; o.y = ev[i][1]; o.z = ev[i][2]; o.w = ev[i][3];
            *(float4*)(eout + (size_t)z * TT * SS + (size_t)(t0 + r0 + i) * SS + s0 + c0) = o;
        }
        __syncthreads();   // kt fully consumed; reuse as e^T
#pragma unroll
        for (int i = 0; i < 4; ++i)
#pragma unroll
            for (int j = 0; j < 4; ++j)
                kt[(c0 + j) * 64 + (r0 + i)] = ev[i][j];
        __syncthreads();
        // P·V: acc[r][d] += e[r][s] * v[s][d]
#pragma unroll 8
        for (int s = 0; s < 64; ++s) {
            const float4 ee = *(const float4*)&kt[s * 64 + r0];
            const float4 vv = *(const float4*)&vs[s * 64 + c0];
            acc[0][0] += ee.x * vv.x; acc[0][1] += ee.x * vv.y; acc[0][2] += ee.x * vv.z; acc[0][3] += ee.x * vv.w;
            acc[1][0] += ee.y * vv.x; acc[1][1] += ee.y * vv.y; acc[1][2] += ee.y * vv.z; acc[1][3] += ee.y * vv.w;
            acc[2][0] += ee.z * vv.x; acc[2][1] += ee.z * vv.y; acc[2][2] += ee.z * vv.z; acc[2][3] += ee.z * vv.w;
            acc[3][0] += ee.w * vv.x; acc[3][1] += ee.w * vv.y; acc[3][2] += ee.w * vv.z; acc[3][3] += ee.w * vv.w;
        }
    }

    // reduce Z across the 16 lanes of the row group
#pragma unroll
    for (int off = 1; off < 16; off <<= 1) {
#pragma unroll
        for (int i = 0; i < 4; ++i)
            zp[i] += __shfl_xor(zp[i], off, 64);
    }
    float rz[4];
#pragma unroll
    for (int i = 0; i < 4; ++i) rz[i] = 1.f / zp[i];

    if ((tid & 15) == 0) {
#pragma unroll
        for (int i = 0; i < 4; ++i)
            rcpz[z * TT + t0 + r0 + i] = rz[i];
    }

#pragma unroll
    for (int i = 0; i < 4; ++i) {
        float4 o;
        o.x = acc[i][0] * rz[i];
        o.y = acc[i][1] * rz[i];
        o.z = acc[i][2] * rz[i];
        o.w = acc[i][3] * rz[i];
        *(float4*)(av + ((size_t)z * TT + t0 + r0 + i) * DD + c0) = o;
    }
}

// ---------------------------------------------------------------------------
// K3: normalize attention weights: w[z,t,s] = e[z,t,s] * rcpz[z,t]
// ---------------------------------------------------------------------------
__global__ __launch_bounds__(256) void norm_kernel(float4* __restrict__ w,
                                                   const float* __restrict__ rz)
{
    const int idx = blockIdx.x * 256 + threadIdx.x;   // float4 index, exact cover
    const float r = rz[idx >> 9];                     // (idx*4) / 2048
    float4 v = w[idx];
    v.x *= r; v.y *= r; v.z *= r; v.w *= r;
    w[idx] = v;
}

// ---------------------------------------------------------------------------
// K4: output projection. out0[R][e] = sum_f X2[R][f]*Wo[e][f] + bo[e]
//     X2[R][f] = av[z=b*H+(f>>6)][t=R>>1][f&63], R = t*B+b
// ---------------------------------------------------------------------------
__global__ __launch_bounds__(256) void oproj_kernel(const float* __restrict__ av,
                                                    const float* __restrict__ Wo,
                                                    const float* __restrict__ bo,
                                                    float* __restrict__ out0)
{
    __shared__ __align__(16) float xt[64 * 64];
    __shared__ __align__(16) float wt[64 * 64];
    const int tid = threadIdx.x;
    const int R0 = blockIdx.x * 64;
    const int C0 = blockIdx.y * 64;
    const int rL = tid >> 2, g = tid & 3;
    const int r0 = (tid >> 4) * 4;
    const int c0 = (tid & 15) * 4;

    float acc[4][4] = {{0.f}};
    for (int kc = 0; kc < 16; ++kc) {
        const int F0 = kc * 64;
        __syncthreads();
        {
            const int R = R0 + rL;
            const int t = R >> 1, b = R & 1;
            const float* src = av + ((size_t)(b * HH + (F0 >> 6)) * TT + t) * DD;
#pragma unroll
            for (int j4 = 0; j4 < 4; ++j4) {
                const int e0 = g * 16 + j4 * 4;
                const float4 val = *(const float4*)(src + e0);
                xt[(e0 + 0) * 64 + rL] = val.x;
                xt[(e0 + 1) * 64 + rL] = val.y;
                xt[(e0 + 2) * 64 + rL] = val.z;
                xt[(e0 + 3) * 64 + rL] = val.w;
            }
        }
        stage_T(Wo + (size_t)C0 * EE + F0, EE, wt, rL, g);
        __syncthreads();
        mm16(xt, wt, r0, c0, acc);
    }

    const float4 bb = *(const float4*)(bo + C0 + c0);
#pragma unroll
    for (int i = 0; i < 4; ++i) {
        const int R = R0 + r0 + i;
        float4 o;
        o.x = acc[i][0] + bb.x;
        o.y = acc[i][1] + bb.y;
        o.z = acc[i][2] + bb.z;
        o.w = acc[i][3] + bb.w;
        *(float4*)(out0 + (size_t)R * EE + C0 + c0) = o;
    }
}

// ---------------------------------------------------------------------------

extern "C" void kernel_launch(void* const* d_in, const int* in_sizes, int n_in,
                              void* d_out, int out_size, void* d_ws, size_t ws_size,
                              hipStream_t stream)
{
    const float* query = (const float*)d_in[0];
    const float* key   = (const float*)d_in[1];
    const float* value = (const float*)d_in[2];
    const int*   mask  = (const int*)d_in[3];
    const float* Wq = (const float*)d_in[4];
    const float* bq = (const float*)d_in[5];
    const float* Wk = (const float*)d_in[6];
    const float* bk = (const float*)d_in[7];
    const float* Wv = (const float*)d_in[8];
    const float* bv = (const float*)d_in[9];
    const float* Wo = (const float*)d_in[10];
    const float* bo = (const float*)d_in[11];

    float* out0 = (float*)d_out;                       // attn [T,B,E]
    float* out1 = out0 + (size_t)TT * BB * EE;         // attn_weights [Z,T,S]

    float* ws  = (float*)d_ws;
    float* qws = ws;                                   // [Z,T,D]
    float* kws = ws + (size_t)ZZ * TT * DD;            // [Z,S,D]
    float* vws = ws + 2 * (size_t)ZZ * TT * DD;        // [Z,S,D]
    float* avs = ws + 3 * (size_t)ZZ * TT * DD;        // [Z,T,D]
    float* rz  = ws + 4 * (size_t)ZZ * TT * DD;        // [Z,T]

    const dim3 blk(256);
    const dim3 gproj(TT * BB / 64, EE / 64);           // (64, 16)
    proj_kernel<<<gproj, blk, 0, stream>>>(query, Wq, bq, qws, SCALING);
    proj_kernel<<<gproj, blk, 0, stream>>>(key,   Wk, bk, kws, 1.0f);
    proj_kernel<<<gproj, blk, 0, stream>>>(value, Wv, bv, vws, 1.0f);

    const dim3 gattn(TT / 64, ZZ);                     // (32, 32)
    attn_kernel<<<gattn, blk, 0, stream>>>(qws, kws, vws, mask, out1, avs, rz);

    norm_kernel<<<dim3((unsigned)((size_t)ZZ * TT * SS / 4 / 256)), blk, 0, stream>>>(
        (float4*)out1, rz);

    oproj_kernel<<<gproj, blk, 0, stream>>>(avs, Wo, bo, out0);
}

// Round 2
// 977.824 us; speedup vs baseline: 2.0025x; 2.0025x over previous
//
#include <hip/hip_runtime.h>
#include <math.h>

// Problem constants
#define TT 2048
#define SS 2048
#define BB 2
#define EE 1024
#define HH 16
#define DD 64
#define ZZ 32
#define SCALING 0.125f
#define D_THRESH 3.8918202981106265f   // log(49)

#define LDP 72   // padded LDS row stride (bf16 elements), keeps 16B alignment

typedef unsigned short ushort_t;
typedef __attribute__((ext_vector_type(8))) short bf16x8;
typedef __attribute__((ext_vector_type(4))) float f32x4;

__device__ __forceinline__ ushort_t f2bf(float f) {
    unsigned u = __float_as_uint(f);
    return (ushort_t)((u + 0x7fffu + ((u >> 16) & 1u)) >> 16);   // RNE
}

// convert 8 consecutive fp32 -> 8 bf16 and store 16B to LDS
__device__ __forceinline__ void cvt_store8(const float* __restrict__ src,
                                           ushort_t* __restrict__ dst) {
    const float4 a = *(const float4*)src;
    const float4 b = *(const float4*)(src + 4);
    union { ushort_t u[8]; bf16x8 v; } t;
    t.u[0] = f2bf(a.x); t.u[1] = f2bf(a.y); t.u[2] = f2bf(a.z); t.u[3] = f2bf(a.w);
    t.u[4] = f2bf(b.x); t.u[5] = f2bf(b.y); t.u[6] = f2bf(b.z); t.u[7] = f2bf(b.w);
    *(bf16x8*)dst = t.v;
}

// ---------------------------------------------------------------------------
// maskpack: mask[T][S] int32 -> bit per element, one u64 per 64 s positions.
// ---------------------------------------------------------------------------
__global__ __launch_bounds__(256) void maskpack_kernel(const int* __restrict__ mask,
                                                       unsigned long long* __restrict__ mb)
{
    const int gw = (blockIdx.x * 256 + threadIdx.x) >> 6;   // global wave id (0..4095)
    const int lane = threadIdx.x & 63;
    for (int i = 0; i < 16; ++i) {
        const size_t w64 = (size_t)gw * 16 + i;             // 0..65535
        const int v = mask[w64 * 64 + lane];
        const unsigned long long b = __ballot(v != 0);
        if (lane == 0) mb[w64] = b;
    }
}

// ---------------------------------------------------------------------------
// projb: C[R][f] = sum_e X[R][e]*W[f][e]; bf16 MFMA, fused fp32->bf16 staging.
// Output bf16 in [z = b*16 + f>>6][t = R>>1][d = f&63], value (C+bias)*scale.
// Grid (32, 8), 256 threads, 128x128 tile, BK=64.
// ---------------------------------------------------------------------------
__global__ __launch_bounds__(256) void projb_kernel(const float* __restrict__ X,
                                                    const float* __restrict__ W,
                                                    const float* __restrict__ bias,
                                                    ushort_t* __restrict__ out,
                                                    float scale)
{
    __shared__ __align__(16) ushort_t Al[128 * LDP];
    __shared__ __align__(16) ushort_t Bl[128 * LDP];
    const int tid = threadIdx.x;
    const int lane = tid & 63, wid = tid >> 6;
    const int ln = lane & 15, quad = lane >> 4;
    const int wrow = (wid >> 1) * 64, wcol = (wid & 1) * 64;
    const int R0 = blockIdx.x * 128, C0 = blockIdx.y * 128;
    const int rL = tid >> 1, half = (tid & 1) * 32;

    f32x4 acc[4][4] = {};
    for (int kc = 0; kc < 16; ++kc) {
        const int E0 = kc * 64;
        __syncthreads();
        {
            const float* sa = X + (size_t)(R0 + rL) * EE + E0 + half;
            const float* sb = W + (size_t)(C0 + rL) * EE + E0 + half;
            ushort_t* da = &Al[rL * LDP + half];
            ushort_t* db = &Bl[rL * LDP + half];
#pragma unroll
            for (int j = 0; j < 4; ++j) cvt_store8(sa + j * 8, da + j * 8);
#pragma unroll
            for (int j = 0; j < 4; ++j) cvt_store8(sb + j * 8, db + j * 8);
        }
        __syncthreads();
#pragma unroll
        for (int ks = 0; ks < 2; ++ks) {
            bf16x8 af[4], bfr[4];
#pragma unroll
            for (int i = 0; i < 4; ++i)
                af[i] = *(const bf16x8*)&Al[(wrow + i * 16 + ln) * LDP + ks * 32 + quad * 8];
#pragma unroll
            for (int i = 0; i < 4; ++i)
                bfr[i] = *(const bf16x8*)&Bl[(wcol + i * 16 + ln) * LDP + ks * 32 + quad * 8];
#pragma unroll
            for (int rt = 0; rt < 4; ++rt)
#pragma unroll
                for (int ct = 0; ct < 4; ++ct)
                    acc[rt][ct] = __builtin_amdgcn_mfma_f32_16x16x32_bf16(
                        af[rt], bfr[ct], acc[rt][ct], 0, 0, 0);
        }
    }
#pragma unroll
    for (int ct = 0; ct < 4; ++ct) {
        const int f = C0 + wcol + ct * 16 + ln;
        const float bv = bias[f];
        const int h = f >> 6, d = f & 63;
#pragma unroll
        for (int rt = 0; rt < 4; ++rt)
#pragma unroll
            for (int reg = 0; reg < 4; ++reg) {
                const int R = R0 + wrow + rt * 16 + quad * 4 + reg;
                const int t = R >> 1, b = R & 1;
                const float v = (acc[rt][ct][reg] + bv) * scale;
                out[((size_t)((b << 4) + h) * TT + t) * DD + d] = f2bf(v);
            }
    }
}

// ---------------------------------------------------------------------------
// vtrans: v bf16 [z][s][d] -> vt bf16 [z][d][s].  Grid (32, 32), 256 thr.
// ---------------------------------------------------------------------------
__global__ __launch_bounds__(256) void vtrans_kernel(const ushort_t* __restrict__ vb,
                                                     ushort_t* __restrict__ vtb)
{
    __shared__ __align__(16) ushort_t tsh[64][LDP];
    const int tid = threadIdx.x;
    const int z = blockIdx.y, s0 = blockIdx.x * 64;
    const int r = tid >> 2, g = (tid & 3) * 16;
    const ushort_t* src = vb + ((size_t)z * SS + s0 + r) * DD + g;
    *(bf16x8*)&tsh[r][g]     = *(const bf16x8*)src;
    *(bf16x8*)&tsh[r][g + 8] = *(const bf16x8*)(src + 8);
    __syncthreads();
    const int d = tid >> 2;
    union { ushort_t u[16]; } t;
#pragma unroll
    for (int j = 0; j < 16; ++j) t.u[j] = tsh[g + j][d];
    ushort_t* dst = vtb + ((size_t)z * DD + d) * SS + s0 + g;
    *(bf16x8*)dst       = *(bf16x8*)&t.u[0];
    *(bf16x8*)(dst + 8) = *(bf16x8*)&t.u[8];
}

// ---------------------------------------------------------------------------
// attnb: flash-style 2-pass MFMA attention.
// Pass A: online (max, Z) over S via QK^T (mask applied; no drop in Z — err <1e-4 rel).
// Pass B: recompute logits, w = kept ? exp(l-m)/Z : 0; write w (fp32) to out1,
//         accumulate O = w·V via MFMA (P round-trips LDS as bf16), store av fp32.
// Block = (z, 64 q rows), 256 threads = 4 waves, wave w owns rows 16w..16w+15.
// ---------------------------------------------------------------------------
__global__ __launch_bounds__(256) void attnb_kernel(const ushort_t* __restrict__ qb,
                                                    const ushort_t* __restrict__ kb,
                                                    const ushort_t* __restrict__ vtb,
                                                    const unsigned long long* __restrict__ mb,
                                                    float* __restrict__ out1,
                                                    float* __restrict__ av)
{
    __shared__ __align__(16) ushort_t Ks[64 * LDP];
    __shared__ __align__(16) ushort_t Vts[64 * LDP];
    __shared__ __align__(16) ushort_t Pl[4][16 * LDP];
    __shared__ unsigned long long Ml[64];
    const int tid = threadIdx.x;
    const int lane = tid & 63, wid = tid >> 6;
    const int ln = lane & 15, quad = lane >> 4;
    const int rr = quad * 4;                       // C-layout row base
    const int z = blockIdx.y, t0 = blockIdx.x * 64;
    const int srL = tid >> 2, sgr = (tid & 3) * 16;

    // persistent Q fragments (A-layout: row = ln, k = d)
    const ushort_t* qrow = qb + ((size_t)z * TT + t0 + wid * 16 + ln) * DD;
    const bf16x8 aq0 = *(const bf16x8*)(qrow + quad * 8);
    const bf16x8 aq1 = *(const bf16x8*)(qrow + 32 + quad * 8);

    float ml[4] = {-1e30f, -1e30f, -1e30f, -1e30f};
    float zl[4] = {0.f, 0.f, 0.f, 0.f};

    // ---------------- pass A ----------------
    for (int st = 0; st < 32; ++st) {
        __syncthreads();
        {
            const ushort_t* src = kb + ((size_t)z * SS + st * 64 + srL) * DD + sgr;
            *(bf16x8*)&Ks[srL * LDP + sgr]     = *(const bf16x8*)src;
            *(bf16x8*)&Ks[srL * LDP + sgr + 8] = *(const bf16x8*)(src + 8);
        }
        if (tid < 64) Ml[tid] = mb[(size_t)(t0 + tid) * 32 + st];
        __syncthreads();
#pragma unroll
        for (int nt = 0; nt < 4; ++nt) {
            const ushort_t* kp = &Ks[(nt * 16 + ln) * LDP + quad * 8];
            const bf16x8 b0 = *(const bf16x8*)kp;
            const bf16x8 b1 = *(const bf16x8*)(kp + 32);
            f32x4 lg = {};
            lg = __builtin_amdgcn_mfma_f32_16x16x32_bf16(aq0, b0, lg, 0, 0, 0);
            lg = __builtin_amdgcn_mfma_f32_16x16x32_bf16(aq1, b1, lg, 0, 0, 0);
#pragma unroll
            for (int reg = 0; reg < 4; ++reg) {
                const unsigned long long w = Ml[wid * 16 + rr + reg];
                const bool keep = (w >> (nt * 16 + ln)) & 1ULL;
                const float l = keep ? lg[reg] : -2e30f;
                const float nm = fmaxf(ml[reg], l);
                zl[reg] = zl[reg] * __expf(ml[reg] - nm) + __expf(l - nm);
                ml[reg] = nm;
            }
        }
    }
    // butterfly combine across the 16 lanes sharing each row
#pragma unroll
    for (int off = 1; off < 16; off <<= 1) {
#pragma unroll
        for (int reg = 0; reg < 4; ++reg) {
            const float om = __shfl_xor(ml[reg], off, 64);
            const float oz = __shfl_xor(zl[reg], off, 64);
            const float nm = fmaxf(ml[reg], om);
            zl[reg] = zl[reg] * __expf(ml[reg] - nm) + oz * __expf(om - nm);
            ml[reg] = nm;
        }
    }
    float rz[4];
#pragma unroll
    for (int reg = 0; reg < 4; ++reg) rz[reg] = 1.f / zl[reg];

    // ---------------- pass B ----------------
    f32x4 o[4] = {};
    for (int st = 0; st < 32; ++st) {
        __syncthreads();
        {
            const ushort_t* ksrc = kb + ((size_t)z * SS + st * 64 + srL) * DD + sgr;
            *(bf16x8*)&Ks[srL * LDP + sgr]     = *(const bf16x8*)ksrc;
            *(bf16x8*)&Ks[srL * LDP + sgr + 8] = *(const bf16x8*)(ksrc + 8);
            const ushort_t* vsrc = vtb + ((size_t)z * DD + srL) * SS + st * 64 + sgr;
            *(bf16x8*)&Vts[srL * LDP + sgr]     = *(const bf16x8*)vsrc;
            *(bf16x8*)&Vts[srL * LDP + sgr + 8] = *(const bf16x8*)(vsrc + 8);
        }
        if (tid < 64) Ml[tid] = mb[(size_t)(t0 + tid) * 32 + st];
        __syncthreads();
#pragma unroll
        for (int nt = 0; nt < 4; ++nt) {
            const ushort_t* kp = &Ks[(nt * 16 + ln) * LDP + quad * 8];
            const bf16x8 b0 = *(const bf16x8*)kp;
            const bf16x8 b1 = *(const bf16x8*)(kp + 32);
            f32x4 lg = {};
            lg = __builtin_amdgcn_mfma_f32_16x16x32_bf16(aq0, b0, lg, 0, 0, 0);
            lg = __builtin_amdgcn_mfma_f32_16x16x32_bf16(aq1, b1, lg, 0, 0, 0);
#pragma unroll
            for (int reg = 0; reg < 4; ++reg) {
                const unsigned long long w = Ml[wid * 16 + rr + reg];
                const bool keep = ((w >> (nt * 16 + ln)) & 1ULL) &&
                                  (lg[reg] >= ml[reg] - D_THRESH);
                const float e = keep ? __expf(lg[reg] - ml[reg]) : 0.f;
                const float wv = e * rz[reg];
                out1[((size_t)z * TT + t0 + wid * 16 + rr + reg) * SS + st * 64 + nt * 16 + ln] = wv;
                Pl[wid][(rr + reg) * LDP + nt * 16 + ln] = f2bf(wv);
            }
        }
        // PV for this 64-s chunk (P is wave-private; no barrier needed)
#pragma unroll
        for (int ks = 0; ks < 2; ++ks) {
            const bf16x8 ap = *(const bf16x8*)&Pl[wid][ln * LDP + ks * 32 + quad * 8];
#pragma unroll
            for (int dt = 0; dt < 4; ++dt) {
                const bf16x8 bv = *(const bf16x8*)&Vts[(dt * 16 + ln) * LDP + ks * 32 + quad * 8];
                o[dt] = __builtin_amdgcn_mfma_f32_16x16x32_bf16(ap, bv, o[dt], 0, 0, 0);
            }
        }
    }
    // store av (fp32, already normalized)
#pragma unroll
    for (int dt = 0; dt < 4; ++dt)
#pragma unroll
        for (int reg = 0; reg < 4; ++reg)
            av[((size_t)z * TT + t0 + wid * 16 + rr + reg) * DD + dt * 16 + ln] = o[dt][reg];
}

// ---------------------------------------------------------------------------
// oprojb: out0[R][e] = sum_f av2[R][f]*Wo[e][f] + bo[e], bf16 MFMA.
// av2[R][f] = av[z = (R&1)*16 + f>>6][t = R>>1][f&63] (fp32, staged->bf16).
// ---------------------------------------------------------------------------
__global__ __launch_bounds__(256) void oprojb_kernel(const float* __restrict__ avp,
                                                     const float* __restrict__ Wo,
                                                     const float* __restrict__ bo,
                                                     float* __restrict__ out0)
{
    __shared__ __align__(16) ushort_t Al[128 * LDP];
    __shared__ __align__(16) ushort_t Bl[128 * LDP];
    const int tid = threadIdx.x;
    const int lane = tid & 63, wid = tid >> 6;
    const int ln = lane & 15, quad = lane >> 4;
    const int wrow = (wid >> 1) * 64, wcol = (wid & 1) * 64;
    const int R0 = blockIdx.x * 128, C0 = blockIdx.y * 128;
    const int rL = tid >> 1, half = (tid & 1) * 32;

    f32x4 acc[4][4] = {};
    for (int kc = 0; kc < 16; ++kc) {
        const int F0 = kc * 64;
        __syncthreads();
        {
            const int R = R0 + rL, t = R >> 1, b = R & 1;
            const float* sa = avp + ((size_t)((b << 4) + kc) * TT + t) * DD + half;
            const float* sb = Wo + (size_t)(C0 + rL) * EE + F0 + half;
            ushort_t* da = &Al[rL * LDP + half];
            ushort_t* db = &Bl[rL * LDP + half];
#pragma unroll
            for (int j = 0; j < 4; ++j) cvt_store8(sa + j * 8, da + j * 8);
#pragma unroll
            for (int j = 0; j < 4; ++j) cvt_store8(sb + j * 8, db + j * 8);
        }
        __syncthreads();
#pragma unroll
        for (int ks = 0; ks < 2; ++ks) {
            bf16x8 af[4], bfr[4];
#pragma unroll
            for (int i = 0; i < 4; ++i)
                af[i] = *(const bf16x8*)&Al[(wrow + i * 16 + ln) * LDP + ks * 32 + quad * 8];
#pragma unroll
            for (int i = 0; i < 4; ++i)
                bfr[i] = *(const bf16x8*)&Bl[(wcol + i * 16 + ln) * LDP + ks * 32 + quad * 8];
#pragma unroll
            for (int rt = 0; rt < 4; ++rt)
#pragma unroll
                for (int ct = 0; ct < 4; ++ct)
                    acc[rt][ct] = __builtin_amdgcn_mfma_f32_16x16x32_bf16(
                        af[rt], bfr[ct], acc[rt][ct], 0, 0, 0);
        }
    }
#pragma unroll
    for (int ct = 0; ct < 4; ++ct) {
        const int e = C0 + wcol + ct * 16 + ln;
        const float bv = bo[e];
#pragma unroll
        for (int rt = 0; rt < 4; ++rt)
#pragma unroll
            for (int reg = 0; reg < 4; ++reg) {
                const int R = R0 + wrow + rt * 16 + quad * 4 + reg;
                out0[(size_t)R * EE + e] = acc[rt][ct][reg] + bv;
            }
    }
}

// ---------------------------------------------------------------------------

extern "C" void kernel_launch(void* const* d_in, const int* in_sizes, int n_in,
                              void* d_out, int out_size, void* d_ws, size_t ws_size,
                              hipStream_t stream)
{
    const float* query = (const float*)d_in[0];
    const float* key   = (const float*)d_in[1];
    const float* value = (const float*)d_in[2];
    const int*   mask  = (const int*)d_in[3];
    const float* Wq = (const float*)d_in[4];
    const float* bq = (const float*)d_in[5];
    const float* Wk = (const float*)d_in[6];
    const float* bk = (const float*)d_in[7];
    const float* Wv = (const float*)d_in[8];
    const float* bv = (const float*)d_in[9];
    const float* Wo = (const float*)d_in[10];
    const float* bo = (const float*)d_in[11];

    float* out0 = (float*)d_out;                        // attn [T,B,E]
    float* out1 = out0 + (size_t)TT * BB * EE;          // attn_weights [Z,T,S]

    char* ws = (char*)d_ws;
    const size_t nzd = (size_t)ZZ * TT * DD;            // 4.19M elements
    ushort_t* qb  = (ushort_t*)ws;                      //  8.4 MB bf16 [z][t][d]
    ushort_t* kb  = qb + nzd;                           //  8.4 MB bf16 [z][s][d]
    ushort_t* vb  = kb + nzd;                           //  8.4 MB bf16 [z][s][d]
    ushort_t* vtb = vb + nzd;                           //  8.4 MB bf16 [z][d][s]
    float*    av  = (float*)(vtb + nzd);                // 16.8 MB fp32 [z][t][d]
    unsigned long long* mb = (unsigned long long*)(av + nzd);  // 512 KB bits

    const dim3 blk(256);

    maskpack_kernel<<<dim3(1024), blk, 0, stream>>>(mask, mb);

    const dim3 gproj(TT * BB / 128, EE / 128);          // (32, 8)
    projb_kernel<<<gproj, blk, 0, stream>>>(query, Wq, bq, qb, SCALING);
    projb_kernel<<<gproj, blk, 0, stream>>>(key,   Wk, bk, kb, 1.0f);
    projb_kernel<<<gproj, blk, 0, stream>>>(value, Wv, bv, vb, 1.0f);

    vtrans_kernel<<<dim3(SS / 64, ZZ), blk, 0, stream>>>(vb, vtb);

    attnb_kernel<<<dim3(TT / 64, ZZ), blk, 0, stream>>>(qb, kb, vtb, mb, out1, av);

    oprojb_kernel<<<gproj, blk, 0, stream>>>(av, Wo, bo, out0);
}